// Round 14
// baseline (158.785 us; speedup 1.0000x reference)
//
#include <hip/hip_runtime.h>
#include <hip/hip_bf16.h>
#include <math.h>

#define NSLICE 2048
#define NH 133     // output spatial size (int(128*1+4)+1)
#define NHH (NH * NH)
#define NP 144     // padded to 9 tiles of 16
#define NT 576     // 9 waves per block
#define SPB 4      // slices per block -> 512 blocks = exactly 2/CU, 1 generation
#define NBLK (NSLICE / SPB)

// LDS map (78,848 B; x2 = 157,696 <= 163,840 -> 2 blocks/CU):
//   [0, 32768)       X_fm   : 32 frags (pt*4+kk) x 1024 B, bf16 fragment-major
//   [32768, 69632)   M1_fm  : 36 frags (it*4+kk) x 1024 B, bf16 fragment-major
//   [69632, 78848)   scratch: 9 waves x 1024 B (per-wave repack)
#define M1B  32768
#define SCR  69632
#define LDSB 78848

typedef __attribute__((ext_vector_type(8))) short bf16x8;   // 8 bf16 = 4 VGPRs
typedef __attribute__((ext_vector_type(4))) float f32x4;

typedef __attribute__((address_space(3))) unsigned int  lds_u32;
typedef const __attribute__((address_space(1))) unsigned int glb_u32;

#define GLOAD_LDS16(gsrc, ldst) \
    __builtin_amdgcn_global_load_lds((glb_u32*)(gsrc), (lds_u32*)(ldst), 16, 0, 0)

__device__ __forceinline__ unsigned f2bf(float f) {
    __hip_bfloat16 h = __float2bfloat16(f);   // round-to-nearest-even
    union { __hip_bfloat16 b; unsigned short u; } c; c.b = h; return (unsigned)c.u;
}

// ---------------------------------------------------------------------------
// prep_M: combined (IDCT * mask * DCT) matrices, bf16, in workspace.
//   M[row, p] = sum_{u=0}^{127} D2[u,row] * mask[u] * D1[u,p]
// M1 emitted FRAGMENT-MAJOR (R10-proven); M2 row-major.
// ---------------------------------------------------------------------------
__global__ void prep_M(const float* __restrict__ rw,
                       unsigned short* __restrict__ M1,
                       unsigned short* __restrict__ M2) {
    __shared__ float t1[512];
    __shared__ float t2[532];
    const int b   = blockIdx.x;        // 0..287
    const int m   = b / NP;            // 0 -> M1, 1 -> M2
    const int row = b - m * NP;        // 0..143
    const int p   = threadIdx.x;       // 0..127

    const float c1  = (float)(M_PI / 256.0);
    const float c2  = (float)(M_PI / 266.0);
    const float s1n = 0.125f;                  // sqrt(2/128)
    const float s10 = 0.08838834764831844f;    // s1n/sqrt(2)
    const float s2n = 0.12262786485246718f;    // sqrt(2/133)
    const float s20 = 0.08671099951921386f;    // s2n/sqrt(2)

    for (int k = p; k < 512; k += 128) t1[k] = cosf((float)k * c1) * s1n;
    for (int k = p; k < 532; k += 128) t2[k] = cosf((float)k * c2) * s2n;
    __syncthreads();

    float val = 0.0f;
    if (row < NH) {
        float r = rw[m];
        float minr = fmaxf((1.0f - 4.0f) / 128.0f, 0.0f);
        r = fminf(fmaxf(r, minr), 2.0f);
        const float crop = 128.0f * r;

        const int tp = 2 * p + 1;
        const int ti = 2 * row + 1;
        float acc = s10 * s20;        // u = 0 term (mask(0) == 1 since crop >= 0)
        int a1 = 0, a2 = 0;
        for (int u = 1; u < 128; ++u) {
            a1 = (a1 + tp) & 511;
            a2 += ti; if (a2 >= 532) a2 -= 532;
            float mask = fminf(fmaxf((4.0f + crop - (float)u) * 0.25f, 0.0f), 1.0f);
            acc = fmaf(t1[a1] * mask, t2[a2], acc);
        }
        val = acc;
    }
    const unsigned short v16 = (unsigned short)f2bf(val);
    if (m == 0) {
        const int it = row >> 4, rr = row & 15;
        const int k2 = p >> 5, gg = (p >> 3) & 3, e = p & 7;
        M1[(size_t)((it * 4 + k2) * 512 + (gg * 16 + rr) * 8 + e)] = v16;
    } else {
        M2[(size_t)row * 128 + p] = v16;
    }
}

// ---------------------------------------------------------------------------
// dct_resize: 512 persistent blocks (2/CU), 9 waves, 4 slices each.
// R10 internals verbatim (all LDS access lane-contiguous fragment-major =
// proven 295K conflicts) + T14 issue-early/write-late cross-slice staging:
//   slice s: [issue 4 asm loads s+1] stage A pt0-3 [issue 4 more] pt4-7
//            repack -> bfrag ; BAR
//            [vmcnt(0); sched_barrier; cvt; ds_write X_fm(s+1)]
//            stage B (M1_fm reads + guarded stores) ; BAR
// Only slice 0's staging latency is exposed, once per kernel (not per block).
// ---------------------------------------------------------------------------
__global__ __launch_bounds__(NT, 5) void dct_resize(
        const float* __restrict__ x,
        const unsigned short* __restrict__ M1f,
        const unsigned short* __restrict__ M2,
        float* __restrict__ out) {
    __shared__ __align__(16) unsigned char lds[LDSB];

    const int tid  = threadIdx.x;
    const int w    = tid >> 6;      // wave 0..8
    const int lane = tid & 63;
    const int r    = lane & 15;     // fragment row/col index
    const int g    = lane >> 4;     // k-group 0..3

    const float* xbase = x   + (size_t)blockIdx.x * SPB * (128 * 128);
    float*       obase = out + (size_t)blockIdx.x * SPB * NHH;

    const int j0 = w * 16;          // this wave's output-column tile

    // per-lane staging source offset for fragment v (wave w stages f=v*8+w):
    // src row = (f>>2)*16 + r, cols (f&3)*32 + g*8 .. +7  (two float4s)
    // global pattern per instruction: 16 rows x full 128B line -> coalesced.
    #define SRCOFF(v) ((size_t)(((((v) * 8 + w) >> 2) * 16 + r) * 128 \
                       + (((v) * 8 + w) & 3) * 32 + g * 8))

    #define ALOAD(dstlo, dsthi, sp) do {                                       \
        asm volatile("global_load_dwordx4 %0, %1, off"                         \
                     : "=v"(dstlo) : "v"(sp) : "memory");                      \
        asm volatile("global_load_dwordx4 %0, %1, off offset:16"               \
                     : "=v"(dsthi) : "v"(sp) : "memory"); } while (0)

    // ---- prologue ----
    #pragma unroll
    for (int v = 0; v < 4; ++v)
        GLOAD_LDS16(M1f + (size_t)(v * NT + tid) * 8,
                    lds + M1B + (v * NT + tid) * 16);

    bf16x8 bm2[4];
    #pragma unroll
    for (int kk = 0; kk < 4; ++kk)
        bm2[kk] = *(const bf16x8*)(M2 + (size_t)(j0 + r) * 128 + kk * 32 + g * 8);

    f32x4 xlo[4], xhi[4];
    if (w < 8) {
        #pragma unroll
        for (int v = 0; v < 4; ++v) ALOAD(xlo[v], xhi[v], xbase + SRCOFF(v));
    }
    asm volatile("s_waitcnt vmcnt(0)" ::: "memory");
    __builtin_amdgcn_sched_barrier(0);

    if (w < 8) {
        #pragma unroll
        for (int v = 0; v < 4; ++v) {
            const int f = v * 8 + w;
            uint4 pkt;
            pkt.x = f2bf(xlo[v].x) | (f2bf(xlo[v].y) << 16);
            pkt.y = f2bf(xlo[v].z) | (f2bf(xlo[v].w) << 16);
            pkt.z = f2bf(xhi[v].x) | (f2bf(xhi[v].y) << 16);
            pkt.w = f2bf(xhi[v].z) | (f2bf(xhi[v].w) << 16);
            *(uint4*)(lds + f * 1024 + lane * 16) = pkt;
        }
    }
    __syncthreads();

    for (int s = 0; s < SPB; ++s) {
        const bool pf = (s + 1 < SPB);

        // ---- issue first half of next slice's loads (hide under stage A) ----
        if (pf && w < 8) {
            const float* nx = xbase + (size_t)(s + 1) * (128 * 128);
            ALOAD(xlo[0], xhi[0], nx + SRCOFF(0));
            ALOAD(xlo[1], xhi[1], nx + SRCOFF(1));
        }

        // ---- Stage A: T[j0+r][p] = sum_q X[p][q] * M2[j0+r][q] ----
        uint2 u2[8];
        #pragma unroll
        for (int pt = 0; pt < 8; ++pt) {
            if (pt == 4 && pf && w < 8) {
                const float* nx = xbase + (size_t)(s + 1) * (128 * 128);
                ALOAD(xlo[2], xhi[2], nx + SRCOFF(2));
                ALOAD(xlo[3], xhi[3], nx + SRCOFF(3));
            }
            f32x4 acc = {0.f, 0.f, 0.f, 0.f};
            #pragma unroll
            for (int kk = 0; kk < 4; ++kk) {
                bf16x8 a = *(const bf16x8*)(lds + (pt * 4 + kk) * 1024 + lane * 16);
                acc = __builtin_amdgcn_mfma_f32_16x16x32_bf16(a, bm2[kk], acc, 0, 0, 0);
            }
            u2[pt].x = f2bf(acc[0]) | (f2bf(acc[1]) << 16);
            u2[pt].y = f2bf(acc[2]) | (f2bf(acc[3]) << 16);
        }

        // ---- per-wave repack: D layout (4-consec p) -> B-frag (8-consec p)
        unsigned char* scr = lds + SCR + w * 1024;
        bf16x8 bfrag[4];
        #pragma unroll
        for (int kk = 0; kk < 4; ++kk) {
            *(uint2*)(scr + (g)     * 128 + r * 8) = u2[2 * kk];
            *(uint2*)(scr + (4 + g) * 128 + r * 8) = u2[2 * kk + 1];
            const uint2 lo2 = *(const uint2*)(scr + (2 * g)     * 128 + r * 8);
            const uint2 hi2 = *(const uint2*)(scr + (2 * g + 1) * 128 + r * 8);
            union { uint4 u; bf16x8 b; } cv;
            cv.u = make_uint4(lo2.x, lo2.y, hi2.x, hi2.y);
            bfrag[kk] = cv.b;
        }

        __syncthreads();   // all waves done reading X_fm (and repack scratch)

        // ---- write next slice into X_fm (loads arrived during stage A) ----
        if (pf) {
            asm volatile("s_waitcnt vmcnt(0)" ::: "memory");
            __builtin_amdgcn_sched_barrier(0);
            if (w < 8) {
                #pragma unroll
                for (int v = 0; v < 4; ++v) {
                    const int f = v * 8 + w;
                    uint4 pkt;
                    pkt.x = f2bf(xlo[v].x) | (f2bf(xlo[v].y) << 16);
                    pkt.y = f2bf(xlo[v].z) | (f2bf(xlo[v].w) << 16);
                    pkt.z = f2bf(xhi[v].x) | (f2bf(xhi[v].y) << 16);
                    pkt.w = f2bf(xhi[v].z) | (f2bf(xhi[v].w) << 16);
                    *(uint4*)(lds + f * 1024 + lane * 16) = pkt;
                }
            }
        }

        // ---- Stage B: out[i][j0+r] = sum_p M1[i][p] * T[j0+r][p] ----
        float* os = obase + (size_t)s * NHH;
        const int jc = j0 + r;
        #pragma unroll
        for (int it = 0; it < 9; ++it) {
            f32x4 acc = {0.f, 0.f, 0.f, 0.f};
            #pragma unroll
            for (int kk = 0; kk < 4; ++kk) {
                bf16x8 a = *(const bf16x8*)(lds + M1B + (it * 4 + kk) * 1024 + lane * 16);
                acc = __builtin_amdgcn_mfma_f32_16x16x32_bf16(a, bfrag[kk], acc, 0, 0, 0);
            }
            if (jc < NH) {
                #pragma unroll
                for (int q = 0; q < 4; ++q) {
                    const int i = it * 16 + g * 4 + q;
                    if (i < NH) os[(size_t)i * NH + jc] = acc[q];
                }
            }
        }

        __syncthreads();   // X_fm(s+1) writes visible before next stage A
    }
    #undef SRCOFF
    #undef ALOAD
}

extern "C" void kernel_launch(void* const* d_in, const int* in_sizes, int n_in,
                              void* d_out, int out_size, void* d_ws, size_t ws_size,
                              hipStream_t stream) {
    const float* x  = (const float*)d_in[0];
    const float* rw = (const float*)d_in[1];
    float* outp = (float*)d_out;
    unsigned short* M1 = (unsigned short*)d_ws;     // 18432 ushorts, fragment-major
    unsigned short* M2 = M1 + 18432;                // 18432 ushorts, row-major

    prep_M<<<dim3(2 * NP), dim3(128), 0, stream>>>(rw, M1, M2);
    dct_resize<<<dim3(NBLK), dim3(NT), 0, stream>>>(x, M1, M2, outp);
}

// Round 15
// 81.333 us; speedup vs baseline: 1.9523x; 1.9523x over previous
//
#include <hip/hip_runtime.h>
#include <hip/hip_bf16.h>
#include <math.h>

#define NSLICE 2048
#define NH 133     // output spatial size (int(128*1+4)+1)
#define NP 144     // padded to 9 tiles of 16
#define NT 576     // 9 waves per block

// LDS map (41,984 B; x3 = 125,952 <= 163,840 -> 3 blocks/CU, 27 waves):
//   [0, 32768)       X_fm   : 32 frags (pt*4+kk) x 1024 B, bf16 fragment-major
//   [32768, 41984)   scratch: 9 waves x 1024 B (per-wave repack)
#define SCR  32768
#define LDSB 41984

typedef __attribute__((ext_vector_type(8))) short bf16x8;   // 8 bf16 = 4 VGPRs
typedef __attribute__((ext_vector_type(4))) float f32x4;

__device__ __forceinline__ unsigned f2bf(float f) {
    __hip_bfloat16 h = __float2bfloat16(f);   // round-to-nearest-even
    union { __hip_bfloat16 b; unsigned short u; } c; c.b = h; return (unsigned)c.u;
}

// ---------------------------------------------------------------------------
// prep_M: combined (IDCT * mask * DCT) matrices, bf16, in workspace.
//   M[row, p] = sum_{u=0}^{127} D2[u,row] * mask[u] * D1[u,p]
// M1 emitted FRAGMENT-MAJOR (R10-proven): frag (it,kk) is 512 ushorts at
//   (it*4+kk)*512 + (((p>>3)&3)*16 + (row&15))*8 + (p&7)
// so a wave's read  M1f + (it*4+kk)*512 + lane*8  is its A-fragment.
// M2 row-major.
// ---------------------------------------------------------------------------
__global__ void prep_M(const float* __restrict__ rw,
                       unsigned short* __restrict__ M1,
                       unsigned short* __restrict__ M2) {
    __shared__ float t1[512];
    __shared__ float t2[532];
    const int b   = blockIdx.x;        // 0..287
    const int m   = b / NP;            // 0 -> M1, 1 -> M2
    const int row = b - m * NP;        // 0..143
    const int p   = threadIdx.x;       // 0..127

    const float c1  = (float)(M_PI / 256.0);
    const float c2  = (float)(M_PI / 266.0);
    const float s1n = 0.125f;                  // sqrt(2/128)
    const float s10 = 0.08838834764831844f;    // s1n/sqrt(2)
    const float s2n = 0.12262786485246718f;    // sqrt(2/133)
    const float s20 = 0.08671099951921386f;    // s2n/sqrt(2)

    for (int k = p; k < 512; k += 128) t1[k] = cosf((float)k * c1) * s1n;
    for (int k = p; k < 532; k += 128) t2[k] = cosf((float)k * c2) * s2n;
    __syncthreads();

    float val = 0.0f;
    if (row < NH) {
        float r = rw[m];
        float minr = fmaxf((1.0f - 4.0f) / 128.0f, 0.0f);
        r = fminf(fmaxf(r, minr), 2.0f);
        const float crop = 128.0f * r;

        const int tp = 2 * p + 1;
        const int ti = 2 * row + 1;
        float acc = s10 * s20;        // u = 0 term (mask(0) == 1 since crop >= 0)
        int a1 = 0, a2 = 0;
        for (int u = 1; u < 128; ++u) {
            a1 = (a1 + tp) & 511;
            a2 += ti; if (a2 >= 532) a2 -= 532;
            float mask = fminf(fmaxf((4.0f + crop - (float)u) * 0.25f, 0.0f), 1.0f);
            acc = fmaf(t1[a1] * mask, t2[a2], acc);
        }
        val = acc;
    }
    const unsigned short v16 = (unsigned short)f2bf(val);
    if (m == 0) {
        const int it = row >> 4, rr = row & 15;
        const int k2 = p >> 5, gg = (p >> 3) & 3, e = p & 7;
        M1[(size_t)((it * 4 + k2) * 512 + (gg * 16 + rr) * 8 + e)] = v16;
    } else {
        M2[(size_t)row * 128 + p] = v16;
    }
}

// ---------------------------------------------------------------------------
// dct_resize: one 576-thread block (9 waves) per (b,c) slice, ONE barrier.
// R10 structure with M1 evicted from LDS (fragment-major GLOBAL reads in
// stage B -- same 36 KB for every wave/block, L1/L2-resident, coalesced
// 1 KB/wave per load).  LDS = 41 KB -> 3 blocks/CU = 27 resident waves:
// the third independent block covers the other two's staging stalls.
//   staging (pre-barrier): waves 0-7 read 32B/lane contiguous fp32, cvt,
//     write X_fm fragment-major (lane*16, conflict-clean: 295K proven)
//   post-barrier, waves fully independent:
//     Stage A: wave w owns j-tile w: 32 MFMA vs reg-resident bm2
//     repack : per-wave 1KB scratch (in-wave DS ordering, barrier-free)
//     Stage B: 36 MFMA, A-frags from global M1f; guarded stores
// ---------------------------------------------------------------------------
__global__ __launch_bounds__(NT, 7) void dct_resize(
        const float* __restrict__ x,
        const unsigned short* __restrict__ M1f,
        const unsigned short* __restrict__ M2,
        float* __restrict__ out) {
    __shared__ __align__(16) unsigned char lds[LDSB];

    const int tid  = threadIdx.x;
    const int w    = tid >> 6;      // wave 0..8
    const int lane = tid & 63;
    const int r    = lane & 15;     // fragment row/col index
    const int g    = lane >> 4;     // k-group 0..3

    const float* xs = x + (size_t)blockIdx.x * (128 * 128);
    float*       os = out + (size_t)blockIdx.x * (NH * NH);

    const int j0 = w * 16;          // this wave's output-column tile

    // ---- per-wave M2 register fragments (L2-hot) ----
    bf16x8 bm2[4];
    #pragma unroll
    for (int kk = 0; kk < 4; ++kk)
        bm2[kk] = *(const bf16x8*)(M2 + (size_t)(j0 + r) * 128 + kk * 32 + g * 8);

    // ---- X staging: waves 0-7, 4 frags each; 32 contiguous B per lane ----
    if (w < 8) {
        #pragma unroll
        for (int v = 0; v < 4; ++v) {
            const int f  = v * 8 + w;        // fragment id 0..31
            const int pt = f >> 2, k2 = f & 3;
            const float* src = xs + (size_t)(pt * 16 + r) * 128 + k2 * 32 + g * 8;
            const float4 lo = *(const float4*)src;
            const float4 hi = *(const float4*)(src + 4);
            uint4 pkt;
            pkt.x = f2bf(lo.x) | (f2bf(lo.y) << 16);
            pkt.y = f2bf(lo.z) | (f2bf(lo.w) << 16);
            pkt.z = f2bf(hi.x) | (f2bf(hi.y) << 16);
            pkt.w = f2bf(hi.z) | (f2bf(hi.w) << 16);
            *(uint4*)(lds + f * 1024 + lane * 16) = pkt;
        }
    }
    __syncthreads();   // the ONLY barrier

    // ---- Stage A: T[j0+r][p] = sum_q X[p][q] * M2[j0+r][q] ----
    uint2 u2[8];
    #pragma unroll
    for (int pt = 0; pt < 8; ++pt) {
        f32x4 acc = {0.f, 0.f, 0.f, 0.f};
        #pragma unroll
        for (int kk = 0; kk < 4; ++kk) {
            bf16x8 a = *(const bf16x8*)(lds + (pt * 4 + kk) * 1024 + lane * 16);
            acc = __builtin_amdgcn_mfma_f32_16x16x32_bf16(a, bm2[kk], acc, 0, 0, 0);
        }
        // lane holds T[j0+r][pt*16 + g*4 + q], q = 0..3 (D layout)
        u2[pt].x = f2bf(acc[0]) | (f2bf(acc[1]) << 16);
        u2[pt].y = f2bf(acc[2]) | (f2bf(acc[3]) << 16);
    }

    // ---- per-wave repack: D layout (4-consec p) -> B-fragment (8-consec p)
    // In-wave DS ops processed in order -> no barrier needed (R4/R10-proven).
    unsigned char* scr = lds + SCR + w * 1024;
    bf16x8 bfrag[4];
    #pragma unroll
    for (int kk = 0; kk < 4; ++kk) {
        *(uint2*)(scr + (g)     * 128 + r * 8) = u2[2 * kk];
        *(uint2*)(scr + (4 + g) * 128 + r * 8) = u2[2 * kk + 1];
        const uint2 lo2 = *(const uint2*)(scr + (2 * g)     * 128 + r * 8);
        const uint2 hi2 = *(const uint2*)(scr + (2 * g + 1) * 128 + r * 8);
        union { uint4 u; bf16x8 b; } cv;
        cv.u = make_uint4(lo2.x, lo2.y, hi2.x, hi2.y);
        bfrag[kk] = cv.b;
    }

    // ---- Stage B: out[i][j0+r] = sum_p M1[i][p] * T[j0+r][p] ----
    // A-fragments from GLOBAL fragment-major M1 (coalesced, L1/L2-hot).
    const int jc = j0 + r;
    #pragma unroll
    for (int it = 0; it < 9; ++it) {
        f32x4 acc = {0.f, 0.f, 0.f, 0.f};
        #pragma unroll
        for (int kk = 0; kk < 4; ++kk) {
            bf16x8 a = *(const bf16x8*)(M1f + (size_t)(it * 4 + kk) * 512 + lane * 8);
            acc = __builtin_amdgcn_mfma_f32_16x16x32_bf16(a, bfrag[kk], acc, 0, 0, 0);
        }
        if (jc < NH) {
            #pragma unroll
            for (int q = 0; q < 4; ++q) {
                const int i = it * 16 + g * 4 + q;
                if (i < NH) os[(size_t)i * NH + jc] = acc[q];
            }
        }
    }
}

extern "C" void kernel_launch(void* const* d_in, const int* in_sizes, int n_in,
                              void* d_out, int out_size, void* d_ws, size_t ws_size,
                              hipStream_t stream) {
    const float* x  = (const float*)d_in[0];
    const float* rw = (const float*)d_in[1];
    float* outp = (float*)d_out;
    unsigned short* M1 = (unsigned short*)d_ws;     // 18432 ushorts, fragment-major
    unsigned short* M2 = M1 + 18432;                // 18432 ushorts, row-major

    prep_M<<<dim3(2 * NP), dim3(128), 0, stream>>>(rw, M1, M2);
    dct_resize<<<dim3(NSLICE), dim3(NT), 0, stream>>>(x, M1, M2, outp);
}